// Round 8
// baseline (469.582 us; speedup 1.0000x reference)
//
#include <hip/hip_runtime.h>
#include <hip/hip_bf16.h>
#include <math.h>

#define SS 4096
#define DE 256
#define DM 64
#define DC 64
#define DIN 320
#define DEPTH 4
#define DT_C 0.1f
#define NSPLIT 12
#define BK 32
#define EXP_SHIFT 8.0f

typedef float f32x4_t __attribute__((ext_vector_type(4)));
typedef __bf16 bf16x8_t __attribute__((ext_vector_type(8)));

#define MFMA_BF16(A, B, C) __builtin_amdgcn_mfma_f32_16x16x32_bf16((A), (B), (C), 0, 0, 0)

// ---------------- output offsets (floats) ----------------
#define OFF_E     (SS*DE)
#define OFF_P     (OFF_E + SS)
#define OFF_G     (OFF_P + SS)
#define OFF_M     (OFF_G + SS)
#define OFF_C     (OFF_M + SS*DM)
#define OFF_L     (OFF_C + SS*DM)
#define OFF_ALIVE (OFF_L + SS)
#define OFF_DIED  (OFF_ALIVE + SS)

// ---------------- ws offsets (float units) ----------------
#define WS_EWS   0                        // SS*DE fp32
#define WS_MWS   (WS_EWS  + SS*DE)        // SS*DM fp32
#define WS_EE    (WS_MWS  + SS*DM)        // SS
#define WS_PP    (WS_EE   + SS)
#define WS_GG    (WS_PP   + SS)
#define WS_LL    (WS_GG   + SS)
#define WS_PL    (WS_LL   + SS)           // NSPLIT*SS fp32
#define WS_POB   (WS_PL   + NSPLIT*SS)    // NSPLIT*SS*DE bf16 (block-native layout)
#define WS_XB    (WS_POB  + NSPLIT*SS*DE/2)
#define WS_QB    (WS_XB   + SS*DIN/2)     // SS*DE bf16
#define WS_KB    (WS_QB   + SS*DE/2)
#define WS_VTB   (WS_KB   + SS*DE/2)      // DE*SS bf16 (transposed V)
#define WS_MB    (WS_VTB  + SS*DE/2)      // SS*DM bf16
#define WS_WT    (WS_MB   + SS*DM/2)      // 3*DEPTH*DE*DIN bf16
#define WS_SEM   (WS_WT   + 3*DEPTH*DE*DIN/2)  // 2 ints (alive count, semaphore)

// LDS strides (bf16 units; byte strides are 16B multiples)
#define KT_STR 264
#define VT_STR 40

// ============== weight transpose: W[z][d][k][n] -> wt[z][d][n][k] bf16 ==============
__global__ __launch_bounds__(256) void transpose_w_kernel(
    const float* __restrict__ wq, const float* __restrict__ wk, const float* __restrict__ wv,
    __hip_bfloat16* __restrict__ wt)
{
    const int zd = blockIdx.z;
    const int z = zd >> 2;
    const float* src = (z == 0 ? wq : (z == 1 ? wk : wv)) + (size_t)(zd & 3) * DIN * DE;
    __shared__ float t[32][33];
    const int k0 = blockIdx.x * 32;      // DIN/32 = 10
    const int n0 = blockIdx.y * 32;      // DE/32  = 8
    const int tr = threadIdx.x >> 5;
    const int tc = threadIdx.x & 31;
    #pragma unroll
    for (int p = 0; p < 4; ++p)
        t[p*8 + tr][tc] = src[(size_t)(k0 + p*8 + tr) * DE + n0 + tc];
    __syncthreads();
    #pragma unroll
    for (int p = 0; p < 4; ++p) {
        int n = n0 + p*8 + tr;
        int k = k0 + tc;
        wt[((size_t)zd * DE + n) * DIN + k] = __float2bfloat16(t[tc][p*8 + tr]);
    }
}

// ====== init: state copies, xb=[bf16(e)|bf16(c)], mb=bf16(m), zero counters ======
__global__ __launch_bounds__(256) void init_kernel(
    const float* __restrict__ e_in, const float* __restrict__ c_in,
    const float* __restrict__ E_in, const float* __restrict__ P_in,
    const float* __restrict__ G_in, const float* __restrict__ l_in,
    const float* __restrict__ m_in,
    float* __restrict__ e_ws, __hip_bfloat16* __restrict__ xb,
    float* __restrict__ E_ws, float* __restrict__ P_ws, float* __restrict__ G_ws,
    float* __restrict__ l_ws, float* __restrict__ m_ws, __hip_bfloat16* __restrict__ mb,
    int* __restrict__ counters)
{
    const int row = blockIdx.x;
    const int tid = threadIdx.x;
    const float v = e_in[(size_t)row * DE + tid];
    e_ws[(size_t)row * DE + tid] = v;
    xb[(size_t)row * DIN + tid] = __float2bfloat16(v);
    if (tid < DC) {
        xb[(size_t)row * DIN + DE + tid] = __float2bfloat16(c_in[(size_t)row * DC + tid]);
        const float mv = m_in[(size_t)row * DM + tid];
        m_ws[(size_t)row * DM + tid] = mv;
        mb[(size_t)row * DM + tid] = __float2bfloat16(mv);
    }
    if (tid == 0) {
        E_ws[row] = E_in[row];
        P_ws[row] = P_in[row];
        G_ws[row] = G_in[row];
        l_ws[row] = l_in[row];
    }
    if (row == 0 && tid < 2) counters[tid] = 0;
}

// ====== projc: [combine layer-1 for own 16 rows] + q/k/v projection (single-z) ======
// Block swizzle: id%8 tracks qblk>>3 so partial reads hit the writing XCD's L2.
__global__ __launch_bounds__(256, 2) void projc_kernel(
    const __hip_bfloat16* __restrict__ part_ob, const float* __restrict__ part_l,
    float* __restrict__ e_ws, __hip_bfloat16* __restrict__ xb,
    float* __restrict__ E_ws, float* __restrict__ P_ws, float* __restrict__ G_ws,
    float* __restrict__ m_ws, __hip_bfloat16* __restrict__ mb, float* __restrict__ l_ws,
    const float* __restrict__ alpha, const float* __restrict__ beta,
    const float* __restrict__ gamma_, const float* __restrict__ basal,
    const __hip_bfloat16* __restrict__ wt,
    const float* __restrict__ bq, const float* __restrict__ bk, const float* __restrict__ bv,
    __hip_bfloat16* __restrict__ qb, __hip_bfloat16* __restrict__ kb, __hip_bfloat16* __restrict__ vtb,
    int layer)
{
    const int id = blockIdx.x;
    const int xcd = id & 7, inner = id >> 3;
    const int qblk = (xcd << 3) | (inner >> 2);
    const int rb = qblk * 4 + (inner & 3);      // row-block of 16
    const int tid = threadIdx.x;

    if (layer > 0) {
        // ---- combine for previous layer's attention: 4 rows per wave ----
        const int wc = tid >> 6, lane = tid & 63;
        const int lp = layer - 1;
        const float a = alpha[lp], bb = beta[lp], gm = gamma_[lp], bas = basal[lp];
        #pragma unroll
        for (int rr = 0; rr < 4; ++rr) {
            const int row = rb * 16 + wc * 4 + rr;
            const int qb2 = row >> 6, wa = (row >> 4) & 3, quada = (row >> 2) & 3, ra = row & 3;
            float L = 0.f;
            #pragma unroll
            for (int s = 0; s < NSPLIT; ++s) L += part_l[s * SS + row];
            const float invL = 1.0f / L;
            const int ct = lane >> 2;
            const int base_off = (ct * 64 + quada * 16 + (lane & 3) * 4) * 4;
            float o[4] = {0.f, 0.f, 0.f, 0.f};
            #pragma unroll
            for (int s = 0; s < NSPLIT; ++s) {
                const size_t region = ((size_t)((s * (SS / 64) + qb2) * 4 + wa)) * 4096;
                const ushort* pp = (const ushort*)(part_ob + region) + base_off;
                ushort vals[16];
                *(uint4*)&vals[0] = *(const uint4*)pp;
                *(uint4*)&vals[8] = *(const uint4*)(pp + 8);
                #pragma unroll
                for (int j = 0; j < 4; ++j)
                    o[j] += __uint_as_float(((unsigned)vals[j * 4 + ra]) << 16);
            }
            const float h0 = o[0] * invL, h1 = o[1] * invL, h2 = o[2] * invL, h3 = o[3] * invL;
            float4 ev = *(float4*)&e_ws[(size_t)row * DE + lane * 4];
            ev.x += h0; ev.y += h1; ev.z += h2; ev.w += h3;
            *(float4*)&e_ws[(size_t)row * DE + lane * 4] = ev;
            __hip_bfloat16 x4[4] = {__float2bfloat16(ev.x), __float2bfloat16(ev.y),
                                    __float2bfloat16(ev.z), __float2bfloat16(ev.w)};
            *(uint2*)&xb[(size_t)row * DIN + lane * 4] = *(uint2*)x4;

            float ssq = h0*h0 + h1*h1 + h2*h2 + h3*h3;
            #pragma unroll
            for (int mask = 1; mask < 64; mask <<= 1) ssq += __shfl_xor(ssq, mask);

            const float E = E_ws[row], P = P_ws[row];
            const float PE = P * E;
            const float Pn = fmaxf(0.f, P + (a * ssq - bb * PE) * DT_C);
            const float En = fmaxf(0.f, E + (bas - gm * PE) * DT_C);
            const float mtg = 1.f / (1.f + __expf(-(En - Pn)));
            const size_t mi = (size_t)row * DM + lane;
            const float mv = 0.9f * m_ws[mi] + 0.1f * mtg;
            m_ws[mi] = mv;
            mb[mi] = __float2bfloat16(mv);
            if (lane == 0) {
                E_ws[row] = En;
                P_ws[row] = Pn;
                G_ws[row] = G_ws[row] + (0.1f * En - 0.5f * Pn) * DT_C;
                const float ldec = 0.01f + 0.5f * fmaxf(0.f, Pn - 2.0f);
                const float lv = l_ws[row] - ldec * DT_C;
                l_ws[row] = fminf(1.f, fmaxf(0.f, lv));
            }
        }
        __syncthreads();   // xb rows ready for proj phase
    }

    // ---- projection: 16 rows x 768 cols (q|k|v), wave covers 192 cols ----
    const int w = tid >> 6, lane = tid & 63;
    const int m = lane & 15, quad = lane >> 4;
    const int row0 = rb * 16;

    bf16x8_t xa[10];
    #pragma unroll
    for (int kk = 0; kk < 10; ++kk)
        xa[kk] = *(const bf16x8_t*)&xb[(size_t)(row0 + m) * DIN + kk * 32 + quad * 8];

    f32x4_t acc[12];
    #pragma unroll
    for (int nt = 0; nt < 12; ++nt) acc[nt] = (f32x4_t){0.f, 0.f, 0.f, 0.f};

    #pragma unroll
    for (int kk = 0; kk < 10; ++kk) {
        #pragma unroll
        for (int nt = 0; nt < 12; ++nt) {
            const int gcol = w * 192 + nt * 16 + m;
            const int z = gcol >> 8, col = gcol & 255;
            bf16x8_t bfrag = *(const bf16x8_t*)&wt[((size_t)(z * DEPTH + layer) * DE + col) * DIN + kk * 32 + quad * 8];
            acc[nt] = MFMA_BF16(xa[kk], bfrag, acc[nt]);
        }
    }
    #pragma unroll
    for (int nt = 0; nt < 12; ++nt) {
        const int gcol = w * 192 + nt * 16 + m;
        const int z = gcol >> 8, col = gcol & 255;
        const float* bias = (z == 0 ? bq : (z == 1 ? bk : bv)) + (size_t)layer * DE;
        const float b = bias[col];
        #pragma unroll
        for (int r = 0; r < 4; ++r) {
            const int row = row0 + quad * 4 + r;
            const __hip_bfloat16 h = __float2bfloat16(acc[nt][r] + b);
            if (z == 0)      qb[(size_t)row * DE + col] = h;
            else if (z == 1) kb[(size_t)row * DE + col] = h;
            else             vtb[(size_t)col * SS + row] = h;
        }
    }
}

// ====== attention: S^T-swapped MFMA flash, transpose-free P path ======
__global__ __launch_bounds__(256, 3) void attn_mfma_kernel(
    const __hip_bfloat16* __restrict__ qb, const __hip_bfloat16* __restrict__ kb,
    const __hip_bfloat16* __restrict__ vtb, const __hip_bfloat16* __restrict__ mb,
    const float* __restrict__ l_ws,
    __hip_bfloat16* __restrict__ part_ob, float* __restrict__ part_l)
{
    __shared__ __align__(16) __hip_bfloat16 kt[32 * KT_STR];   // 16896 B
    __shared__ __align__(16) __hip_bfloat16 vt[256 * VT_STR];  // 20480 B

    const int id = blockIdx.x;
    const int split = id >> 6;
    const int rid = id & 63;
    const int qblk = (rid & 7) * 8 + (rid >> 3);   // id%8 == qblk>>3 -> XCD locality

    const int tid = threadIdx.x;
    const int w = tid >> 6, lane = tid & 63;
    const int n = lane & 15, quad = lane >> 4;
    const int row0 = qblk * 64 + w * 16;

    bf16x8_t qa[8];
    #pragma unroll
    for (int kk = 0; kk < 8; ++kk)
        qa[kk] = *(const bf16x8_t*)&qb[(size_t)(row0 + n) * DE + kk * 32 + quad * 8];
    bf16x8_t ma[2];
    #pragma unroll
    for (int kk = 0; kk < 2; ++kk)
        ma[kk] = *(const bf16x8_t*)&mb[(size_t)(row0 + n) * DM + kk * 32 + quad * 8];
    const float lqs = l_ws[row0 + n] * 0.0625f;   // fold 1/sqrt(DE); qrow = n

    f32x4_t oacc[16];
    #pragma unroll
    for (int ct = 0; ct < 16; ++ct) oacc[ct] = (f32x4_t){0.f, 0.f, 0.f, 0.f};
    float plsum = 0.f;
    const f32x4_t zf4 = (f32x4_t){0.f, 0.f, 0.f, 0.f};

    const int k_row = tid >> 5, k_g = tid & 31;
    const int v_col = tid >> 2, v_seg = tid & 3;
    const int v_base = (v_seg & 1) * 16 + (v_seg >> 1) * 4;   // kappa-permuted base

    const int it_begin = (split * 128) / NSPLIT;
    const int it_end   = ((split + 1) * 128) / NSPLIT;

    for (int it = it_begin; it < it_end; ++it) {
        const int t0 = it * BK;
        __syncthreads();
        #pragma unroll
        for (int p = 0; p < 4; ++p) {   // K tile: 32 rows x 256 bf16
            const int row = k_row + p * 8;
            *(float4*)&kt[row * KT_STR + k_g * 8] = *(const float4*)&kb[(size_t)(t0 + row) * DE + k_g * 8];
        }
        #pragma unroll
        for (int p = 0; p < 4; ++p) {   // V^T tile, kappa-permuted keys
            const int col = v_col + p * 64;
            const float4 f = *(const float4*)&vtb[(size_t)col * SS + t0 + v_seg * 8];
            *(float2*)&vt[col * VT_STR + v_base]     = make_float2(f.x, f.y);
            *(float2*)&vt[col * VT_STR + v_base + 8] = make_float2(f.z, f.w);
        }
        __syncthreads();

        // m/l direct from global (L2-hot)
        const bf16x8_t mf00 = *(const bf16x8_t*)&mb[(size_t)(t0 + n) * DM + quad * 8];
        const bf16x8_t mf01 = *(const bf16x8_t*)&mb[(size_t)(t0 + n) * DM + 32 + quad * 8];
        const bf16x8_t mf10 = *(const bf16x8_t*)&mb[(size_t)(t0 + n + 16) * DM + quad * 8];
        const bf16x8_t mf11 = *(const bf16x8_t*)&mb[(size_t)(t0 + n + 16) * DM + 32 + quad * 8];
        const float4 lk0 = *(const float4*)&l_ws[t0 + quad * 4];
        const float4 lk1 = *(const float4*)&l_ws[t0 + 16 + quad * 4];

        // S^T = K Q^T : 4 independent 4-deep chains
        f32x4_t s0a = zf4, s0b = zf4, s1a = zf4, s1b = zf4;
        #pragma unroll
        for (int kk = 0; kk < 4; ++kk) {
            bf16x8_t k0 = *(const bf16x8_t*)&kt[n * KT_STR + kk * 32 + quad * 8];
            bf16x8_t k1 = *(const bf16x8_t*)&kt[(n + 16) * KT_STR + kk * 32 + quad * 8];
            s0a = MFMA_BF16(k0, qa[kk], s0a);
            s1a = MFMA_BF16(k1, qa[kk], s1a);
        }
        #pragma unroll
        for (int kk = 4; kk < 8; ++kk) {
            bf16x8_t k0 = *(const bf16x8_t*)&kt[n * KT_STR + kk * 32 + quad * 8];
            bf16x8_t k1 = *(const bf16x8_t*)&kt[(n + 16) * KT_STR + kk * 32 + quad * 8];
            s0b = MFMA_BF16(k0, qa[kk], s0b);
            s1b = MFMA_BF16(k1, qa[kk], s1b);
        }
        const f32x4_t st0 = s0a + s0b;
        const f32x4_t st1 = s1a + s1b;

        // membrane^T: 2-deep chains
        f32x4_t mm0 = MFMA_BF16(mf00, ma[0], zf4);
        mm0 = MFMA_BF16(mf01, ma[1], mm0);
        f32x4_t mm1 = MFMA_BF16(mf10, ma[0], zf4);
        mm1 = MFMA_BF16(mf11, ma[1], mm1);

        // scores -> p ; P is the PV A-fragment directly (kappa order)
        bf16x8_t pa;
        #pragma unroll
        for (int r = 0; r < 4; ++r) {
            const float x0 = st0[r] * lqs * lk0[r] * mm0[r];
            const float x1 = st1[r] * lqs * lk1[r] * mm1[r];
            const float p0 = __expf(x0 - EXP_SHIFT);
            const float p1 = __expf(x1 - EXP_SHIFT);
            plsum += p0 + p1;
            pa[r]     = (__bf16)p0;
            pa[4 + r] = (__bf16)p1;
        }

        #pragma unroll
        for (int ct = 0; ct < 16; ++ct) {
            bf16x8_t vb = *(const bf16x8_t*)&vt[(ct * 16 + n) * VT_STR + quad * 8];
            oacc[ct] = MFMA_BF16(pa, vb, oacc[ct]);
        }
    }

    // ---- epilogue ----
    plsum += __shfl_xor(plsum, 16);
    plsum += __shfl_xor(plsum, 32);
    if (lane < 16)
        part_l[split * SS + row0 + lane] = plsum;

    __hip_bfloat16* dst = part_ob + ((size_t)((split * (SS / 64) + qblk) * 4 + w)) * 4096;
    #pragma unroll
    for (int ct = 0; ct < 16; ++ct) {
        __hip_bfloat16 h4[4];
        #pragma unroll
        for (int r = 0; r < 4; ++r) h4[r] = __float2bfloat16(oacc[ct][r]);
        *(uint2*)&dst[(ct * 64 + lane) * 4] = *(uint2*)h4;
    }
}

// ====== finalizec: combine layer-3 + ODE + mask + pack + num_died ======
__global__ __launch_bounds__(256) void finalizec_kernel(
    const __hip_bfloat16* __restrict__ part_ob, const float* __restrict__ part_l,
    const float* __restrict__ e_ws,
    const float* __restrict__ E_ws, const float* __restrict__ P_ws, const float* __restrict__ G_ws,
    const float* __restrict__ m_ws, const float* __restrict__ c_in, const float* __restrict__ l_ws,
    const float* __restrict__ alpha, const float* __restrict__ beta,
    const float* __restrict__ gamma_, const float* __restrict__ basal,
    float* __restrict__ out, int* __restrict__ counters)
{
    const int id = blockIdx.x;
    const int xcd = id & 7, inner = id >> 3;
    const int qblk = (xcd << 3) | (inner >> 2);
    const int rb = qblk * 4 + (inner & 3);
    const int tid = threadIdx.x;
    const int wc = tid >> 6, lane = tid & 63;

    const int lp = DEPTH - 1;
    const float a = alpha[lp], bb = beta[lp], gm = gamma_[lp], bas = basal[lp];

    __shared__ int s_alive[4];
    int alive_cnt = 0;

    #pragma unroll
    for (int rr = 0; rr < 4; ++rr) {
        const int row = rb * 16 + wc * 4 + rr;
        const int qb2 = row >> 6, wa = (row >> 4) & 3, quada = (row >> 2) & 3, ra = row & 3;
        float L = 0.f;
        #pragma unroll
        for (int s = 0; s < NSPLIT; ++s) L += part_l[s * SS + row];
        const float invL = 1.0f / L;
        const int ct = lane >> 2;
        const int base_off = (ct * 64 + quada * 16 + (lane & 3) * 4) * 4;
        float o[4] = {0.f, 0.f, 0.f, 0.f};
        #pragma unroll
        for (int s = 0; s < NSPLIT; ++s) {
            const size_t region = ((size_t)((s * (SS / 64) + qb2) * 4 + wa)) * 4096;
            const ushort* pp = (const ushort*)(part_ob + region) + base_off;
            ushort vals[16];
            *(uint4*)&vals[0] = *(const uint4*)pp;
            *(uint4*)&vals[8] = *(const uint4*)(pp + 8);
            #pragma unroll
            for (int j = 0; j < 4; ++j)
                o[j] += __uint_as_float(((unsigned)vals[j * 4 + ra]) << 16);
        }
        const float h0 = o[0] * invL, h1 = o[1] * invL, h2 = o[2] * invL, h3 = o[3] * invL;
        float4 ev = *(const float4*)&e_ws[(size_t)row * DE + lane * 4];
        ev.x += h0; ev.y += h1; ev.z += h2; ev.w += h3;

        float ssq = h0*h0 + h1*h1 + h2*h2 + h3*h3;
        #pragma unroll
        for (int mask = 1; mask < 64; mask <<= 1) ssq += __shfl_xor(ssq, mask);

        const float E = E_ws[row], P = P_ws[row];
        const float PE = P * E;
        const float Pn = fmaxf(0.f, P + (a * ssq - bb * PE) * DT_C);
        const float En = fmaxf(0.f, E + (bas - gm * PE) * DT_C);
        const float mtg = 1.f / (1.f + __expf(-(En - Pn)));
        const float mv = 0.9f * m_ws[(size_t)row * DM + lane] + 0.1f * mtg;
        const float Gn = G_ws[row] + (0.1f * En - 0.5f * Pn) * DT_C;
        const float ldec = 0.01f + 0.5f * fmaxf(0.f, Pn - 2.0f);
        const float lv = fminf(1.f, fmaxf(0.f, l_ws[row] - ldec * DT_C));
        const float af = (lv > 0.05f) ? 1.f : 0.f;

        float4 eo = make_float4(ev.x * af, ev.y * af, ev.z * af, ev.w * af);
        *(float4*)&out[(size_t)row * DE + lane * 4] = eo;
        out[OFF_M + (size_t)row * DM + lane] = mv * af;
        out[OFF_C + (size_t)row * DM + lane] = c_in[(size_t)row * DM + lane] * af;
        if (lane == 0) {
            out[OFF_E + row] = En * af;
            out[OFF_P + row] = Pn * af;
            out[OFF_G + row] = Gn * af;
            out[OFF_L + row] = lv * af;
            out[OFF_ALIVE + row] = af;
            alive_cnt += (af > 0.f) ? 1 : 0;
        }
    }

    if (lane == 0) s_alive[wc] = alive_cnt;
    __syncthreads();
    if (tid == 0) {
        const int blk_alive = s_alive[0] + s_alive[1] + s_alive[2] + s_alive[3];
        atomicAdd(&counters[0], blk_alive);
        __threadfence();
        const int old = atomicAdd(&counters[1], 1);
        if (old == 255) {
            __threadfence();
            const int tot = atomicAdd(&counters[0], 0);
            out[OFF_DIED] = (float)(SS - tot);
        }
    }
}

extern "C" void kernel_launch(void* const* d_in, const int* in_sizes, int n_in,
                              void* d_out, int out_size, void* d_ws, size_t ws_size,
                              hipStream_t stream) {
    const float* e_in = (const float*)d_in[0];
    const float* E_in = (const float*)d_in[1];
    const float* P_in = (const float*)d_in[2];
    const float* G_in = (const float*)d_in[3];
    const float* m_in = (const float*)d_in[4];
    const float* c_in = (const float*)d_in[5];
    const float* l_in = (const float*)d_in[6];
    const float* wq = (const float*)d_in[7];
    const float* bq = (const float*)d_in[8];
    const float* wk = (const float*)d_in[9];
    const float* bk = (const float*)d_in[10];
    const float* wv = (const float*)d_in[11];
    const float* bv = (const float*)d_in[12];
    const float* alpha = (const float*)d_in[13];
    const float* beta  = (const float*)d_in[14];
    const float* gamma_ = (const float*)d_in[15];
    const float* basal = (const float*)d_in[16];
    float* out = (float*)d_out;
    float* ws = (float*)d_ws;

    float* e_ws = ws + WS_EWS;
    float* m_ws = ws + WS_MWS;
    float* E_ws = ws + WS_EE;
    float* P_ws = ws + WS_PP;
    float* G_ws = ws + WS_GG;
    float* l_ws = ws + WS_LL;
    float* part_l = ws + WS_PL;
    __hip_bfloat16* part_ob = (__hip_bfloat16*)(ws + WS_POB);
    __hip_bfloat16* xb  = (__hip_bfloat16*)(ws + WS_XB);
    __hip_bfloat16* qb  = (__hip_bfloat16*)(ws + WS_QB);
    __hip_bfloat16* kb  = (__hip_bfloat16*)(ws + WS_KB);
    __hip_bfloat16* vtb = (__hip_bfloat16*)(ws + WS_VTB);
    __hip_bfloat16* mb  = (__hip_bfloat16*)(ws + WS_MB);
    __hip_bfloat16* wt  = (__hip_bfloat16*)(ws + WS_WT);
    int* counters = (int*)(ws + WS_SEM);

    transpose_w_kernel<<<dim3(DIN/32, DE/32, 12), 256, 0, stream>>>(wq, wk, wv, wt);
    init_kernel<<<dim3(SS), 256, 0, stream>>>(
        e_in, c_in, E_in, P_in, G_in, l_in, m_in,
        e_ws, xb, E_ws, P_ws, G_ws, l_ws, m_ws, mb, counters);

    for (int layer = 0; layer < DEPTH; ++layer) {
        projc_kernel<<<dim3(SS/16), 256, 0, stream>>>(
            part_ob, part_l, e_ws, xb, E_ws, P_ws, G_ws, m_ws, mb, l_ws,
            alpha, beta, gamma_, basal, wt, bq, bk, bv, qb, kb, vtb, layer);
        attn_mfma_kernel<<<dim3((SS/64) * NSPLIT), 256, 0, stream>>>(
            qb, kb, vtb, mb, l_ws, part_ob, part_l);
    }
    finalizec_kernel<<<dim3(SS/16), 256, 0, stream>>>(
        part_ob, part_l, e_ws, E_ws, P_ws, G_ws, m_ws, c_in, l_ws,
        alpha, beta, gamma_, basal, out, counters);
}

// Round 9
// 415.321 us; speedup vs baseline: 1.1306x; 1.1306x over previous
//
#include <hip/hip_runtime.h>
#include <hip/hip_bf16.h>
#include <math.h>

#define SS 4096
#define DE 256
#define DM 64
#define DC 64
#define DIN 320
#define DEPTH 4
#define DT_C 0.1f
#define NSPLIT 12
#define BK 32
#define EXP_SHIFT 8.0f

typedef float f32x4_t __attribute__((ext_vector_type(4)));
typedef __bf16 bf16x8_t __attribute__((ext_vector_type(8)));

#define MFMA_BF16(A, B, C) __builtin_amdgcn_mfma_f32_16x16x32_bf16((A), (B), (C), 0, 0, 0)

// ---------------- output offsets (floats) ----------------
#define OFF_E     (SS*DE)
#define OFF_P     (OFF_E + SS)
#define OFF_G     (OFF_P + SS)
#define OFF_M     (OFF_G + SS)
#define OFF_C     (OFF_M + SS*DM)
#define OFF_L     (OFF_C + SS*DM)
#define OFF_ALIVE (OFF_L + SS)
#define OFF_DIED  (OFF_ALIVE + SS)

// ---------------- ws offsets (float units) ----------------
#define WS_EWS   0                        // SS*DE fp32
#define WS_MWS   (WS_EWS  + SS*DE)        // SS*DM fp32
#define WS_EE    (WS_MWS  + SS*DM)        // SS
#define WS_PP    (WS_EE   + SS)
#define WS_GG    (WS_PP   + SS)
#define WS_LL    (WS_GG   + SS)
#define WS_PL    (WS_LL   + SS)           // NSPLIT*SS fp32
#define WS_POB   (WS_PL   + NSPLIT*SS)    // NSPLIT*SS*DE bf16 (block-native layout)
#define WS_XB    (WS_POB  + NSPLIT*SS*DE/2)
#define WS_QB    (WS_XB   + SS*DIN/2)     // SS*DE bf16
#define WS_KB    (WS_QB   + SS*DE/2)
#define WS_VTB   (WS_KB   + SS*DE/2)      // DE*SS bf16 (transposed V)
#define WS_MB    (WS_VTB  + SS*DE/2)      // SS*DM bf16
#define WS_WT    (WS_MB   + SS*DM/2)      // 3*DEPTH*DE*DIN bf16
#define WS_SEM   (WS_WT   + 3*DEPTH*DE*DIN/2)  // 2 ints

// LDS strides (bf16 units)
#define KT_STR 264
#define VT_STR 40
#define PJ_STR 72   // proj tile stride: 64 k + 8 pad (144 B rows, 2-way-free banks)

// ============== weight transpose: W[z][d][k][n] -> wt[z][d][n][k] bf16 ==============
__global__ __launch_bounds__(256) void transpose_w_kernel(
    const float* __restrict__ wq, const float* __restrict__ wk, const float* __restrict__ wv,
    __hip_bfloat16* __restrict__ wt)
{
    const int zd = blockIdx.z;
    const int z = zd >> 2;
    const float* src = (z == 0 ? wq : (z == 1 ? wk : wv)) + (size_t)(zd & 3) * DIN * DE;
    __shared__ float t[32][33];
    const int k0 = blockIdx.x * 32;      // DIN/32 = 10
    const int n0 = blockIdx.y * 32;      // DE/32  = 8
    const int tr = threadIdx.x >> 5;
    const int tc = threadIdx.x & 31;
    #pragma unroll
    for (int p = 0; p < 4; ++p)
        t[p*8 + tr][tc] = src[(size_t)(k0 + p*8 + tr) * DE + n0 + tc];
    __syncthreads();
    #pragma unroll
    for (int p = 0; p < 4; ++p) {
        int n = n0 + p*8 + tr;
        int k = k0 + tc;
        wt[((size_t)zd * DE + n) * DIN + k] = __float2bfloat16(t[tc][p*8 + tr]);
    }
}

// ====== init: state copies, xb=[bf16(e)|bf16(c)], mb=bf16(m), zero counters ======
__global__ __launch_bounds__(256) void init_kernel(
    const float* __restrict__ e_in, const float* __restrict__ c_in,
    const float* __restrict__ E_in, const float* __restrict__ P_in,
    const float* __restrict__ G_in, const float* __restrict__ l_in,
    const float* __restrict__ m_in,
    float* __restrict__ e_ws, __hip_bfloat16* __restrict__ xb,
    float* __restrict__ E_ws, float* __restrict__ P_ws, float* __restrict__ G_ws,
    float* __restrict__ l_ws, float* __restrict__ m_ws, __hip_bfloat16* __restrict__ mb,
    int* __restrict__ counters)
{
    const int row = blockIdx.x;
    const int tid = threadIdx.x;
    const float v = e_in[(size_t)row * DE + tid];
    e_ws[(size_t)row * DE + tid] = v;
    xb[(size_t)row * DIN + tid] = __float2bfloat16(v);
    if (tid < DC) {
        xb[(size_t)row * DIN + DE + tid] = __float2bfloat16(c_in[(size_t)row * DC + tid]);
        const float mv = m_in[(size_t)row * DM + tid];
        m_ws[(size_t)row * DM + tid] = mv;
        mb[(size_t)row * DM + tid] = __float2bfloat16(mv);
    }
    if (tid == 0) {
        E_ws[row] = E_in[row];
        P_ws[row] = P_in[row];
        G_ws[row] = G_in[row];
        l_ws[row] = l_in[row];
    }
    if (row == 0 && tid < 2) counters[tid] = 0;
}

// ====== proj GEMM: [4096 x 768] = xb[4096 x 320] @ wt^T, 64x64 tiles, LDS-staged ======
__global__ __launch_bounds__(256, 4) void proj_gemm_kernel(
    const __hip_bfloat16* __restrict__ xb, const __hip_bfloat16* __restrict__ wt,
    const float* __restrict__ bq, const float* __restrict__ bk, const float* __restrict__ bv,
    __hip_bfloat16* __restrict__ qb, __hip_bfloat16* __restrict__ kb, __hip_bfloat16* __restrict__ vtb,
    int layer)
{
    __shared__ __align__(16) __hip_bfloat16 at[64 * PJ_STR];   // 9216 B
    __shared__ __align__(16) __hip_bfloat16 bt[64 * PJ_STR];   // 9216 B
    __shared__ __align__(16) __hip_bfloat16 tt[64 * PJ_STR];   // transpose buffer (z=2)

    const int mt = blockIdx.x;           // 0..63
    const int nt4 = blockIdx.y;          // 0..11
    const int row0 = mt * 64;
    const int z = nt4 >> 2;              // 0=q 1=k 2=v
    const int coln0 = (nt4 & 3) * 64;    // col within z-output
    const __hip_bfloat16* wrow = wt + ((size_t)(z * DEPTH + layer) * DE + coln0) * DIN;

    const int tid = threadIdx.x;
    const int w = tid >> 6, lane = tid & 63;
    const int ml = lane & 15, quad = lane >> 4;
    const int s_r = tid >> 2, s_g = tid & 3;   // staging: 4 threads/row, 16 bf16 each

    f32x4_t acc[4];
    #pragma unroll
    for (int nt = 0; nt < 4; ++nt) acc[nt] = (f32x4_t){0.f, 0.f, 0.f, 0.f};

    for (int k0 = 0; k0 < DIN; k0 += 64) {
        __syncthreads();
        {   // A tile: 64 rows x 64 k
            const __hip_bfloat16* src = &xb[(size_t)(row0 + s_r) * DIN + k0 + s_g * 16];
            *(float4*)&at[s_r * PJ_STR + s_g * 16]     = *(const float4*)src;
            *(float4*)&at[s_r * PJ_STR + s_g * 16 + 8] = *(const float4*)(src + 8);
        }
        {   // B tile: 64 n-rows x 64 k
            const __hip_bfloat16* src = &wrow[(size_t)s_r * DIN + k0 + s_g * 16];
            *(float4*)&bt[s_r * PJ_STR + s_g * 16]     = *(const float4*)src;
            *(float4*)&bt[s_r * PJ_STR + s_g * 16 + 8] = *(const float4*)(src + 8);
        }
        __syncthreads();
        #pragma unroll
        for (int kk = 0; kk < 2; ++kk) {
            const bf16x8_t a = *(const bf16x8_t*)&at[(w * 16 + ml) * PJ_STR + kk * 32 + quad * 8];
            #pragma unroll
            for (int nt = 0; nt < 4; ++nt) {
                const bf16x8_t b = *(const bf16x8_t*)&bt[(nt * 16 + ml) * PJ_STR + kk * 32 + quad * 8];
                acc[nt] = MFMA_BF16(a, b, acc[nt]);
            }
        }
    }

    const float* bias = (z == 0 ? bq : (z == 1 ? bk : bv)) + (size_t)layer * DE;
    if (z < 2) {
        __hip_bfloat16* O = (z == 0 ? qb : kb);
        #pragma unroll
        for (int nt = 0; nt < 4; ++nt) {
            const int col = coln0 + nt * 16 + ml;
            const float b = bias[col];
            #pragma unroll
            for (int r = 0; r < 4; ++r)
                O[(size_t)(row0 + w * 16 + quad * 4 + r) * DE + col] = __float2bfloat16(acc[nt][r] + b);
        }
    } else {
        // transpose 64x64 tile through LDS, then coalesced vtb stores
        #pragma unroll
        for (int nt = 0; nt < 4; ++nt) {
            const int n = nt * 16 + ml;
            const float b = bias[coln0 + n];
            #pragma unroll
            for (int r = 0; r < 4; ++r)
                tt[n * PJ_STR + w * 16 + quad * 4 + r] = __float2bfloat16(acc[nt][r] + b);
        }
        __syncthreads();
        const int c = tid >> 2, seg = tid & 3;   // 4 threads/col, 16 rows each
        __hip_bfloat16* dst = &vtb[(size_t)(coln0 + c) * SS + row0 + seg * 16];
        *(float4*)dst       = *(const float4*)&tt[c * PJ_STR + seg * 16];
        *(float4*)(dst + 8) = *(const float4*)&tt[c * PJ_STR + seg * 16 + 8];
    }
}

// ====== attention: S^T-swapped MFMA flash, transpose-free P path ======
__global__ __launch_bounds__(256, 3) void attn_mfma_kernel(
    const __hip_bfloat16* __restrict__ qb, const __hip_bfloat16* __restrict__ kb,
    const __hip_bfloat16* __restrict__ vtb, const __hip_bfloat16* __restrict__ mb,
    const float* __restrict__ l_ws,
    __hip_bfloat16* __restrict__ part_ob, float* __restrict__ part_l)
{
    __shared__ __align__(16) __hip_bfloat16 kt[32 * KT_STR];   // 16896 B
    __shared__ __align__(16) __hip_bfloat16 vt[256 * VT_STR];  // 20480 B

    const int id = blockIdx.x;
    const int split = id >> 6;
    const int rid = id & 63;
    const int qblk = (rid & 7) * 8 + (rid >> 3);

    const int tid = threadIdx.x;
    const int w = tid >> 6, lane = tid & 63;
    const int n = lane & 15, quad = lane >> 4;
    const int row0 = qblk * 64 + w * 16;

    bf16x8_t qa[8];
    #pragma unroll
    for (int kk = 0; kk < 8; ++kk)
        qa[kk] = *(const bf16x8_t*)&qb[(size_t)(row0 + n) * DE + kk * 32 + quad * 8];
    bf16x8_t ma[2];
    #pragma unroll
    for (int kk = 0; kk < 2; ++kk)
        ma[kk] = *(const bf16x8_t*)&mb[(size_t)(row0 + n) * DM + kk * 32 + quad * 8];
    const float lqs = l_ws[row0 + n] * 0.0625f;

    f32x4_t oacc[16];
    #pragma unroll
    for (int ct = 0; ct < 16; ++ct) oacc[ct] = (f32x4_t){0.f, 0.f, 0.f, 0.f};
    float plsum = 0.f;
    const f32x4_t zf4 = (f32x4_t){0.f, 0.f, 0.f, 0.f};

    const int k_row = tid >> 5, k_g = tid & 31;
    const int v_col = tid >> 2, v_seg = tid & 3;
    const int v_base = (v_seg & 1) * 16 + (v_seg >> 1) * 4;

    const int it_begin = (split * 128) / NSPLIT;
    const int it_end   = ((split + 1) * 128) / NSPLIT;

    for (int it = it_begin; it < it_end; ++it) {
        const int t0 = it * BK;
        __syncthreads();
        #pragma unroll
        for (int p = 0; p < 4; ++p) {
            const int row = k_row + p * 8;
            *(float4*)&kt[row * KT_STR + k_g * 8] = *(const float4*)&kb[(size_t)(t0 + row) * DE + k_g * 8];
        }
        #pragma unroll
        for (int p = 0; p < 4; ++p) {
            const int col = v_col + p * 64;
            const float4 f = *(const float4*)&vtb[(size_t)col * SS + t0 + v_seg * 8];
            *(float2*)&vt[col * VT_STR + v_base]     = make_float2(f.x, f.y);
            *(float2*)&vt[col * VT_STR + v_base + 8] = make_float2(f.z, f.w);
        }
        __syncthreads();

        const bf16x8_t mf00 = *(const bf16x8_t*)&mb[(size_t)(t0 + n) * DM + quad * 8];
        const bf16x8_t mf01 = *(const bf16x8_t*)&mb[(size_t)(t0 + n) * DM + 32 + quad * 8];
        const bf16x8_t mf10 = *(const bf16x8_t*)&mb[(size_t)(t0 + n + 16) * DM + quad * 8];
        const bf16x8_t mf11 = *(const bf16x8_t*)&mb[(size_t)(t0 + n + 16) * DM + 32 + quad * 8];
        const float4 lk0 = *(const float4*)&l_ws[t0 + quad * 4];
        const float4 lk1 = *(const float4*)&l_ws[t0 + 16 + quad * 4];

        f32x4_t s0a = zf4, s0b = zf4, s1a = zf4, s1b = zf4;
        #pragma unroll
        for (int kk = 0; kk < 4; ++kk) {
            bf16x8_t k0 = *(const bf16x8_t*)&kt[n * KT_STR + kk * 32 + quad * 8];
            bf16x8_t k1 = *(const bf16x8_t*)&kt[(n + 16) * KT_STR + kk * 32 + quad * 8];
            s0a = MFMA_BF16(k0, qa[kk], s0a);
            s1a = MFMA_BF16(k1, qa[kk], s1a);
        }
        #pragma unroll
        for (int kk = 4; kk < 8; ++kk) {
            bf16x8_t k0 = *(const bf16x8_t*)&kt[n * KT_STR + kk * 32 + quad * 8];
            bf16x8_t k1 = *(const bf16x8_t*)&kt[(n + 16) * KT_STR + kk * 32 + quad * 8];
            s0b = MFMA_BF16(k0, qa[kk], s0b);
            s1b = MFMA_BF16(k1, qa[kk], s1b);
        }
        const f32x4_t st0 = s0a + s0b;
        const f32x4_t st1 = s1a + s1b;

        f32x4_t mm0 = MFMA_BF16(mf00, ma[0], zf4);
        mm0 = MFMA_BF16(mf01, ma[1], mm0);
        f32x4_t mm1 = MFMA_BF16(mf10, ma[0], zf4);
        mm1 = MFMA_BF16(mf11, ma[1], mm1);

        bf16x8_t pa;
        #pragma unroll
        for (int r = 0; r < 4; ++r) {
            const float x0 = st0[r] * lqs * lk0[r] * mm0[r];
            const float x1 = st1[r] * lqs * lk1[r] * mm1[r];
            const float p0 = __expf(x0 - EXP_SHIFT);
            const float p1 = __expf(x1 - EXP_SHIFT);
            plsum += p0 + p1;
            pa[r]     = (__bf16)p0;
            pa[4 + r] = (__bf16)p1;
        }

        #pragma unroll
        for (int ct = 0; ct < 16; ++ct) {
            bf16x8_t vb = *(const bf16x8_t*)&vt[(ct * 16 + n) * VT_STR + quad * 8];
            oacc[ct] = MFMA_BF16(pa, vb, oacc[ct]);
        }
    }

    plsum += __shfl_xor(plsum, 16);
    plsum += __shfl_xor(plsum, 32);
    if (lane < 16)
        part_l[split * SS + row0 + lane] = plsum;

    __hip_bfloat16* dst = part_ob + ((size_t)((split * (SS / 64) + qblk) * 4 + w)) * 4096;
    #pragma unroll
    for (int ct = 0; ct < 16; ++ct) {
        __hip_bfloat16 h4[4];
        #pragma unroll
        for (int r = 0; r < 4; ++r) h4[r] = __float2bfloat16(oacc[ct][r]);
        *(uint2*)&dst[(ct * 64 + lane) * 4] = *(uint2*)h4;
    }
}

// ====== combine: sum partials, normalize, e update, xb rebuild, ODE ======
__global__ __launch_bounds__(256) void combine_kernel(
    const __hip_bfloat16* __restrict__ part_ob, const float* __restrict__ part_l,
    float* __restrict__ e_ws, __hip_bfloat16* __restrict__ xb,
    float* __restrict__ E_ws, float* __restrict__ P_ws, float* __restrict__ G_ws,
    float* __restrict__ m_ws, __hip_bfloat16* __restrict__ mb, float* __restrict__ l_ws,
    const float* __restrict__ alpha, const float* __restrict__ beta,
    const float* __restrict__ gamma_, const float* __restrict__ basal, int layer)
{
    const int wc = threadIdx.x >> 6, lane = threadIdx.x & 63;
    const int row = blockIdx.x * 4 + wc;
    const int qblk = row >> 6, wa = (row >> 4) & 3, quada = (row >> 2) & 3, ra = row & 3;

    float L = 0.f;
    #pragma unroll
    for (int s = 0; s < NSPLIT; ++s) L += part_l[s * SS + row];
    const float invL = 1.0f / L;

    const int ct = lane >> 2;
    const int base_off = (ct * 64 + quada * 16 + (lane & 3) * 4) * 4;
    float o[4] = {0.f, 0.f, 0.f, 0.f};
    #pragma unroll
    for (int s = 0; s < NSPLIT; ++s) {
        const size_t region = ((size_t)((s * (SS / 64) + qblk) * 4 + wa)) * 4096;
        const ushort* pp = (const ushort*)(part_ob + region) + base_off;
        ushort vals[16];
        *(uint4*)&vals[0] = *(const uint4*)pp;
        *(uint4*)&vals[8] = *(const uint4*)(pp + 8);
        #pragma unroll
        for (int j = 0; j < 4; ++j)
            o[j] += __uint_as_float(((unsigned)vals[j * 4 + ra]) << 16);
    }
    float h0 = o[0] * invL, h1 = o[1] * invL, h2 = o[2] * invL, h3 = o[3] * invL;

    float4 ev = *(float4*)&e_ws[(size_t)row * DE + lane * 4];
    ev.x += h0; ev.y += h1; ev.z += h2; ev.w += h3;
    *(float4*)&e_ws[(size_t)row * DE + lane * 4] = ev;
    {
        __hip_bfloat16 x4[4] = {__float2bfloat16(ev.x), __float2bfloat16(ev.y),
                                __float2bfloat16(ev.z), __float2bfloat16(ev.w)};
        *(uint2*)&xb[(size_t)row * DIN + lane * 4] = *(uint2*)x4;
    }

    float ssq = h0*h0 + h1*h1 + h2*h2 + h3*h3;
    #pragma unroll
    for (int mask = 1; mask < 64; mask <<= 1) ssq += __shfl_xor(ssq, mask);

    const float a = alpha[layer], b = beta[layer], gm = gamma_[layer], bas = basal[layer];
    const float E = E_ws[row], P = P_ws[row];
    const float PE = P * E;
    const float Pn = fmaxf(0.f, P + (a * ssq - b * PE) * DT_C);
    const float En = fmaxf(0.f, E + (bas - gm * PE) * DT_C);
    const float mtg = 1.f / (1.f + __expf(-(En - Pn)));
    const size_t mi = (size_t)row * DM + lane;
    const float mv = 0.9f * m_ws[mi] + 0.1f * mtg;
    m_ws[mi] = mv;
    mb[mi] = __float2bfloat16(mv);
    if (lane == 0) {
        E_ws[row] = En;
        P_ws[row] = Pn;
        G_ws[row] = G_ws[row] + (0.1f * En - 0.5f * Pn) * DT_C;
        const float ldec = 0.01f + 0.5f * fmaxf(0.f, Pn - 2.0f);
        const float lv = l_ws[row] - ldec * DT_C;
        l_ws[row] = fminf(1.f, fmaxf(0.f, lv));
    }
}

// ====== finalizec: combine last layer + ODE + mask + pack + num_died ======
__global__ __launch_bounds__(256) void finalizec_kernel(
    const __hip_bfloat16* __restrict__ part_ob, const float* __restrict__ part_l,
    const float* __restrict__ e_ws,
    const float* __restrict__ E_ws, const float* __restrict__ P_ws, const float* __restrict__ G_ws,
    const float* __restrict__ m_ws, const float* __restrict__ c_in, const float* __restrict__ l_ws,
    const float* __restrict__ alpha, const float* __restrict__ beta,
    const float* __restrict__ gamma_, const float* __restrict__ basal,
    float* __restrict__ out, int* __restrict__ counters)
{
    const int rb = blockIdx.x;
    const int tid = threadIdx.x;
    const int wc = tid >> 6, lane = tid & 63;

    const int lp = DEPTH - 1;
    const float a = alpha[lp], bb = beta[lp], gm = gamma_[lp], bas = basal[lp];

    __shared__ int s_alive[4];
    int alive_cnt = 0;

    #pragma unroll
    for (int rr = 0; rr < 4; ++rr) {
        const int row = rb * 16 + wc * 4 + rr;
        const int qb2 = row >> 6, wa = (row >> 4) & 3, quada = (row >> 2) & 3, ra = row & 3;
        float L = 0.f;
        #pragma unroll
        for (int s = 0; s < NSPLIT; ++s) L += part_l[s * SS + row];
        const float invL = 1.0f / L;
        const int ct = lane >> 2;
        const int base_off = (ct * 64 + quada * 16 + (lane & 3) * 4) * 4;
        float o[4] = {0.f, 0.f, 0.f, 0.f};
        #pragma unroll
        for (int s = 0; s < NSPLIT; ++s) {
            const size_t region = ((size_t)((s * (SS / 64) + qb2) * 4 + wa)) * 4096;
            const ushort* pp = (const ushort*)(part_ob + region) + base_off;
            ushort vals[16];
            *(uint4*)&vals[0] = *(const uint4*)pp;
            *(uint4*)&vals[8] = *(const uint4*)(pp + 8);
            #pragma unroll
            for (int j = 0; j < 4; ++j)
                o[j] += __uint_as_float(((unsigned)vals[j * 4 + ra]) << 16);
        }
        const float h0 = o[0] * invL, h1 = o[1] * invL, h2 = o[2] * invL, h3 = o[3] * invL;
        float4 ev = *(const float4*)&e_ws[(size_t)row * DE + lane * 4];
        ev.x += h0; ev.y += h1; ev.z += h2; ev.w += h3;

        float ssq = h0*h0 + h1*h1 + h2*h2 + h3*h3;
        #pragma unroll
        for (int mask = 1; mask < 64; mask <<= 1) ssq += __shfl_xor(ssq, mask);

        const float E = E_ws[row], P = P_ws[row];
        const float PE = P * E;
        const float Pn = fmaxf(0.f, P + (a * ssq - bb * PE) * DT_C);
        const float En = fmaxf(0.f, E + (bas - gm * PE) * DT_C);
        const float mtg = 1.f / (1.f + __expf(-(En - Pn)));
        const float mv = 0.9f * m_ws[(size_t)row * DM + lane] + 0.1f * mtg;
        const float Gn = G_ws[row] + (0.1f * En - 0.5f * Pn) * DT_C;
        const float ldec = 0.01f + 0.5f * fmaxf(0.f, Pn - 2.0f);
        const float lv = fminf(1.f, fmaxf(0.f, l_ws[row] - ldec * DT_C));
        const float af = (lv > 0.05f) ? 1.f : 0.f;

        float4 eo = make_float4(ev.x * af, ev.y * af, ev.z * af, ev.w * af);
        *(float4*)&out[(size_t)row * DE + lane * 4] = eo;
        out[OFF_M + (size_t)row * DM + lane] = mv * af;
        out[OFF_C + (size_t)row * DM + lane] = c_in[(size_t)row * DM + lane] * af;
        if (lane == 0) {
            out[OFF_E + row] = En * af;
            out[OFF_P + row] = Pn * af;
            out[OFF_G + row] = Gn * af;
            out[OFF_L + row] = lv * af;
            out[OFF_ALIVE + row] = af;
            alive_cnt += (af > 0.f) ? 1 : 0;
        }
    }

    if (lane == 0) s_alive[wc] = alive_cnt;
    __syncthreads();
    if (tid == 0) {
        const int blk_alive = s_alive[0] + s_alive[1] + s_alive[2] + s_alive[3];
        atomicAdd(&counters[0], blk_alive);
        __threadfence();
        const int old = atomicAdd(&counters[1], 1);
        if (old == 255) {
            __threadfence();
            const int tot = atomicAdd(&counters[0], 0);
            out[OFF_DIED] = (float)(SS - tot);
        }
    }
}

extern "C" void kernel_launch(void* const* d_in, const int* in_sizes, int n_in,
                              void* d_out, int out_size, void* d_ws, size_t ws_size,
                              hipStream_t stream) {
    const float* e_in = (const float*)d_in[0];
    const float* E_in = (const float*)d_in[1];
    const float* P_in = (const float*)d_in[2];
    const float* G_in = (const float*)d_in[3];
    const float* m_in = (const float*)d_in[4];
    const float* c_in = (const float*)d_in[5];
    const float* l_in = (const float*)d_in[6];
    const float* wq = (const float*)d_in[7];
    const float* bq = (const float*)d_in[8];
    const float* wk = (const float*)d_in[9];
    const float* bk = (const float*)d_in[10];
    const float* wv = (const float*)d_in[11];
    const float* bv = (const float*)d_in[12];
    const float* alpha = (const float*)d_in[13];
    const float* beta  = (const float*)d_in[14];
    const float* gamma_ = (const float*)d_in[15];
    const float* basal = (const float*)d_in[16];
    float* out = (float*)d_out;
    float* ws = (float*)d_ws;

    float* e_ws = ws + WS_EWS;
    float* m_ws = ws + WS_MWS;
    float* E_ws = ws + WS_EE;
    float* P_ws = ws + WS_PP;
    float* G_ws = ws + WS_GG;
    float* l_ws = ws + WS_LL;
    float* part_l = ws + WS_PL;
    __hip_bfloat16* part_ob = (__hip_bfloat16*)(ws + WS_POB);
    __hip_bfloat16* xb  = (__hip_bfloat16*)(ws + WS_XB);
    __hip_bfloat16* qb  = (__hip_bfloat16*)(ws + WS_QB);
    __hip_bfloat16* kb  = (__hip_bfloat16*)(ws + WS_KB);
    __hip_bfloat16* vtb = (__hip_bfloat16*)(ws + WS_VTB);
    __hip_bfloat16* mb  = (__hip_bfloat16*)(ws + WS_MB);
    __hip_bfloat16* wt  = (__hip_bfloat16*)(ws + WS_WT);
    int* counters = (int*)(ws + WS_SEM);

    transpose_w_kernel<<<dim3(DIN/32, DE/32, 12), 256, 0, stream>>>(wq, wk, wv, wt);
    init_kernel<<<dim3(SS), 256, 0, stream>>>(
        e_in, c_in, E_in, P_in, G_in, l_in, m_in,
        e_ws, xb, E_ws, P_ws, G_ws, l_ws, m_ws, mb, counters);

    for (int layer = 0; layer < DEPTH; ++layer) {
        proj_gemm_kernel<<<dim3(SS/64, 12), 256, 0, stream>>>(
            xb, wt, bq, bk, bv, qb, kb, vtb, layer);
        attn_mfma_kernel<<<dim3((SS/64) * NSPLIT), 256, 0, stream>>>(
            qb, kb, vtb, mb, l_ws, part_ob, part_l);
        if (layer < DEPTH - 1)
            combine_kernel<<<dim3(SS/4), 256, 0, stream>>>(
                part_ob, part_l, e_ws, xb, E_ws, P_ws, G_ws, m_ws, mb, l_ws,
                alpha, beta, gamma_, basal, layer);
    }
    finalizec_kernel<<<dim3(SS/16), 256, 0, stream>>>(
        part_ob, part_l, e_ws, E_ws, P_ws, G_ws, m_ws, c_in, l_ws,
        alpha, beta, gamma_, basal, out, counters);
}